// Round 14
// baseline (43.750 us; speedup 1.0000x reference)
//
#include <hip/hip_runtime.h>

// LocallyConnectedGC: out[bt, m] = sum_n x[bt, n] * (S*W)[n, m] + b[m]
// S = band mask, half-width 4, ring of 208 -> 9 weights per output column.
//
// R13 = R12 + FORCED band-register residence.
//  R12's pre-loop LDS->reg band read was rematerialized back into the tile
//  loop by the compiler (VGPR stayed 36; conflicts only -25%): steady state
//  stayed 12 ds_read_b128/thread/tile, LDS pipe ~80% of cycle budget.
//  Fix: launder bnd[] through asm ("+v") after loading — values become
//  opaque, cannot be re-read from LDS, must stay in VGPRs.
//  Steady state: 3 ds_read_b128/thread/tile (x only) + 36 FMA + 1 nt store.
//  - Block = 832 threads (13 waves) stages one 16x208 tile/step via
//    global_load_lds (zero-VGPR prefetch), double-buffered, counted
//    vmcnt(1) + raw s_barrier (NO __syncthreads in loop).

#define NN   208
#define NC   52          // NN/4 float4 chunks per row
#define HW   4
#define BAND 9
#define TR   16          // rows per tile
#define THREADS 832      // = TR*NC threads: 13 waves
#define NBLK 512
#define TILE_F  (TR * NN)     // 3328 floats per tile

typedef float vfloat4 __attribute__((ext_vector_type(4)));

__global__ __launch_bounds__(THREADS) void lcgc_kernel(
    const float* __restrict__ x,
    const float* __restrict__ W,
    const float* __restrict__ b,
    const float* __restrict__ S,
    float* __restrict__ out,
    int total_rows)
{
    __shared__ float sX[2][TILE_F];      // 26.6 KB double-buffered x tile
    __shared__ float sBand[BAND * NN];   // 7.5 KB masked weight band

    const int tid = threadIdx.x;

    // One-time cooperative band build (coalesced over m; W/S L2-hot).
    for (int i = tid; i < BAND * NN; i += THREADS) {
        int d = i / NN;
        int m = i - d * NN;
        int n = m + d - HW;
        if (n < 0) n += NN;
        else if (n >= NN) n -= NN;
        sBand[i] = W[n * NN + m] * S[n * NN + m];
    }
    __syncthreads();   // before any staging: full drain here is fine

    const int c    = tid % NC;           // fixed column chunk
    const int rg   = tid / NC;           // row within tile, 0..15
    const int wave = tid >> 6;

    // Band + bias into registers ONCE, then LAUNDER so the compiler cannot
    // rematerialize the LDS reads inside the tile loop (R12 failed here).
    float4 bnd[BAND];
    {
        const float4* band4 = reinterpret_cast<const float4*>(sBand);
        #pragma unroll
        for (int d = 0; d < BAND; ++d) bnd[d] = band4[d * NC + c];
    }
    #pragma unroll
    for (int d = 0; d < BAND; ++d)
        asm volatile("" : "+v"(bnd[d].x), "+v"(bnd[d].y),
                          "+v"(bnd[d].z), "+v"(bnd[d].w));
    float4 bias4 = *reinterpret_cast<const float4*>(&b[c * 4]);
    asm volatile("" : "+v"(bias4.x), "+v"(bias4.y),
                      "+v"(bias4.z), "+v"(bias4.w));

    const int cm = (c == 0)      ? NC - 1 : c - 1;
    const int cp = (c == NC - 1) ? 0      : c + 1;

    const long long ntiles_total = total_rows / TR;          // 8192
    const long long nt = ntiles_total / gridDim.x;           // 16 (runtime)
    const long long t0 = (long long)blockIdx.x * nt;

    // Wave-uniform LDS bases for staging (HW writes base + lane*16).
    float* const ldst0 = &sX[0][wave * 256];   // wave*64 float4 = wave*256 floats
    float* const ldst1 = &sX[1][wave * 256];

    #define STAGE(kt, bi)                                                     \
        do {                                                                  \
            const float* gsrc = x + (t0 + (kt)) * TILE_F + (long long)tid * 4;\
            __builtin_amdgcn_global_load_lds(                                 \
                (const __attribute__((address_space(1))) void*)(gsrc),        \
                (__attribute__((address_space(3))) void*)((bi) ? ldst1 : ldst0),\
                16, 0, 0);                                                    \
        } while (0)

    #define COMPUTE(kt, bi)                                                   \
        do {                                                                  \
            const float4* xr4 =                                               \
                reinterpret_cast<const float4*>(&sX[(bi)][rg * NN]);          \
            const float4 a = xr4[cm];                                         \
            const float4 m4 = xr4[c];                                         \
            const float4 e = xr4[cp];                                         \
            const float xv[12] = {a.x, a.y, a.z, a.w,                         \
                                  m4.x, m4.y, m4.z, m4.w,                     \
                                  e.x, e.y, e.z, e.w};                        \
            float4 acc = bias4;                                               \
            _Pragma("unroll")                                                 \
            for (int d = 0; d < BAND; ++d) {                                  \
                acc.x = fmaf(bnd[d].x, xv[0 + d], acc.x);                     \
                acc.y = fmaf(bnd[d].y, xv[1 + d], acc.y);                     \
                acc.z = fmaf(bnd[d].z, xv[2 + d], acc.z);                     \
                acc.w = fmaf(bnd[d].w, xv[3 + d], acc.w);                     \
            }                                                                 \
            vfloat4 av = {acc.x, acc.y, acc.z, acc.w};                        \
            __builtin_nontemporal_store(av, reinterpret_cast<vfloat4*>(       \
                out + (t0 + (kt)) * TILE_F + rg * NN + c * 4));               \
        } while (0)

    // Prologue: stage tile 0 into buffer 0.
    STAGE(0, 0);

    for (long long k = 0; k < nt - 1; ++k) {
        STAGE(k + 1, (int)((k + 1) & 1));
        // Wait for tile k's loads; leaves tile k+1's staging in flight.
        asm volatile("s_waitcnt vmcnt(1)" ::: "memory");
        __builtin_amdgcn_sched_barrier(0);
        __builtin_amdgcn_s_barrier();      // all waves' tile-k data visible
        COMPUTE(k, (int)(k & 1));
        asm volatile("" ::: "memory");
        __builtin_amdgcn_s_barrier();      // everyone done reading buf k&1
    }
    // Epilogue: last tile, nothing left to prefetch.
    asm volatile("s_waitcnt vmcnt(0)" ::: "memory");
    __builtin_amdgcn_sched_barrier(0);
    __builtin_amdgcn_s_barrier();
    COMPUTE(nt - 1, (int)((nt - 1) & 1));

    #undef STAGE
    #undef COMPUTE
}

extern "C" void kernel_launch(void* const* d_in, const int* in_sizes, int n_in,
                              void* d_out, int out_size, void* d_ws, size_t ws_size,
                              hipStream_t stream) {
    const float* x = (const float*)d_in[0];
    const float* W = (const float*)d_in[1];
    const float* b = (const float*)d_in[2];
    const float* S = (const float*)d_in[3];
    float* out = (float*)d_out;

    const int total_rows = in_sizes[0] / NN;   // 131072 = 8192 tiles of 16
    lcgc_kernel<<<dim3(NBLK), dim3(THREADS), 0, stream>>>(
        x, W, b, S, out, total_rows);
}